// Round 4
// baseline (70.309 us; speedup 1.0000x reference)
//
#include <hip/hip_runtime.h>

typedef _Float16 h2 __attribute__((ext_vector_type(2)));
typedef unsigned int uint32;
typedef unsigned short ushort16;

#define NVAL 20
#define CDIM 64
#define HW   65536
#define NPIX (4*HW)

#define BLK   512                 // pixels (= threads) per block
#define NWAVE (BLK/64)
#define MAXTILES 28               // sum ceil(n_k/64) <= 512/64 + 19 < 28
#define MAXSLOT  (MAXTILES*64)

// ---- global f16 table layout in ws (bytes); rows read via SCALAR loads ----
#define KN_OFF      0
#define KN_KSTRIDE  2560          // per class: 20 j-rows x 128 B (64 f16, c-contig)
#define VAL_OFF     (KN_OFF + 20*KN_KSTRIDE)
#define VAL_KSTRIDE 3072          // per class: 64 c-rows x 48 B (11 h2 pairs + pad)

// ---- LDS layout (bytes) ----
#define ROWS_OFF  0               // BLK rows x 136 B (32 dwords cn-f16, 2 pad)
#define ROWS_BYTES (BLK*136)      // 69632
#define INV_OFF   ROWS_BYTES      // BLK f32
#define PERM_OFF  (INV_OFF + BLK*4)         // MAXSLOT ushort
#define TCLS_OFF  (PERM_OFF + MAXSLOT*2)    // MAXTILES int
#define CNT_OFF   (TCLS_OFF + MAXTILES*4)   // 21 int
#define BASE_OFF  (CNT_OFF + 21*4)          // 21 int
#define NT_OFF    (BASE_OFF + 21*4)         // 1 int
#define LDS_TOTAL (NT_OFF + 16)             // ~75.6 KB -> 2 blocks/CU

static __device__ __forceinline__ h2 bch2(uint32 u) {
    return __builtin_bit_cast(h2, u);
}
static __device__ __forceinline__ uint32 bcu(h2 v) {
    return __builtin_bit_cast(uint32, v);
}
// cvt_pkrtz returns __fp16v2 on this clang; bit_cast to our h2 (_Float16v2).
static __device__ __forceinline__ h2 pkrtz(float a, float b) {
    return __builtin_bit_cast(h2, __builtin_amdgcn_cvt_pkrtz(a, b));
}
static __device__ __forceinline__ float dot2acc(h2 a, h2 b, float acc) {
#if defined(__has_builtin)
#if __has_builtin(__builtin_amdgcn_fdot2)
    return __builtin_amdgcn_fdot2(a, b, acc, false);
#else
    return acc + (float)a[0]*(float)b[0] + (float)a[1]*(float)b[1];
#endif
#else
    return acc + (float)a[0]*(float)b[0] + (float)a[1]*(float)b[1];
#endif
}

// ---------------------------------------------------------------------------
// Prep: build packed f16 tables in ws.
//  threads [0,1280): (k,c) -> V row: 10 j-pairs + (rest,0) pair + pad
//  threads [1280,1680): (k,j) -> normalized key column (c-contig f16 pairs)
// ---------------------------------------------------------------------------
__global__ void prep_kernel(const float* __restrict__ key,
                            const float* __restrict__ val,
                            unsigned char* __restrict__ ws) {
    int i = blockIdx.x * 256 + threadIdx.x;
    if (i < 20*CDIM) {
        int k = i >> 6, c = i & 63;
        const float* vb = val + k*NVAL*CDIM + c;     // val[k][j][c]
        float v[NVAL];
        float s = 0.f;
        #pragma unroll
        for (int j = 0; j < NVAL; j++) { v[j] = vb[j*CDIM]; s += v[j]; }
        float t = 0.f;
        for (int kk = 0; kk < 20; kk++) {
            const float* vb2 = val + kk*NVAL*CDIM + c;
            #pragma unroll
            for (int j = 0; j < NVAL; j++) t += vb2[j*CDIM];
        }
        float rest = (t - s) * (1.0f/NVAL);
        uint32* row = (uint32*)(ws + VAL_OFF + (size_t)k*VAL_KSTRIDE + c*48);
        #pragma unroll
        for (int jp = 0; jp < 10; jp++) row[jp] = bcu(pkrtz(v[2*jp], v[2*jp+1]));
        row[10] = bcu(pkrtz(rest, 0.f));
        row[11] = 0u;
    } else if (i < 20*CDIM + 20*NVAL) {
        int idx = i - 20*CDIM;
        int k = idx / NVAL, j = idx % NVAL;
        const float* kb = key + k*CDIM*NVAL + j;     // key[k][c][j]
        float x[CDIM];
        float ssq = 0.f;
        #pragma unroll
        for (int c = 0; c < CDIM; c++) { x[c] = kb[c*NVAL]; ssq = fmaf(x[c], x[c], ssq); }
        float inv = 1.0f / fmaxf(sqrtf(ssq), 1e-12f);
        uint32* row = (uint32*)(ws + KN_OFF + (size_t)k*KN_KSTRIDE + j*128);
        #pragma unroll
        for (int cp = 0; cp < 32; cp++) row[cp] = bcu(pkrtz(x[2*cp]*inv, x[2*cp+1]*inv));
    }
}

// ---------------------------------------------------------------------------
// Main: 512 blocks x 512 threads. Per block: counting-sort pixels by class
// into class-pure 64-pixel tiles; content staged coalesced into LDS f16 rows;
// tiles stream K/V tables via wave-uniform (scalar) loads; results written
// back into the same LDS rows; final coalesced f32 store.
// ---------------------------------------------------------------------------
__global__ __launch_bounds__(BLK, 4) void main_kernel(
        const float* __restrict__ content, const int* __restrict__ seg,
        const unsigned char* __restrict__ tabs, float* __restrict__ out) {
    extern __shared__ unsigned char lds[];
    float* invA   = (float*)(lds + INV_OFF);
    unsigned short* perm = (unsigned short*)(lds + PERM_OFF);
    int* tcls = (int*)(lds + TCLS_OFF);
    int* cnt  = (int*)(lds + CNT_OFF);
    int* base = (int*)(lds + BASE_OFF);
    int* ntp  = (int*)(lds + NT_OFF);

    const int tid  = threadIdx.x;
    const int gp0  = blockIdx.x * BLK;
    const int b    = gp0 >> 16;
    const int pim0 = gp0 & (HW - 1);

    if (tid < 21) cnt[tid] = 0;
    for (int i = tid; i < MAXSLOT; i += BLK) perm[i] = 0xFFFFu;
    __syncthreads();

    const int cls = seg[gp0 + tid] + 1;          // 1..19
    const int myrank = atomicAdd(&cnt[cls], 1);

    // stage content -> LDS row (f16 pairs) + inv, coalesced reads
    {
        const float* cptr = content + (size_t)b * CDIM * HW + pim0 + tid;
        uint2* myrow = (uint2*)lds + tid * 17;
        float ssq = 0.f;
        #pragma unroll
        for (int q = 0; q < 16; q++) {
            float f0 = cptr[(size_t)(4*q+0) * HW];
            float f1 = cptr[(size_t)(4*q+1) * HW];
            float f2 = cptr[(size_t)(4*q+2) * HW];
            float f3 = cptr[(size_t)(4*q+3) * HW];
            ssq = fmaf(f0,f0,ssq); ssq = fmaf(f1,f1,ssq);
            ssq = fmaf(f2,f2,ssq); ssq = fmaf(f3,f3,ssq);
            uint2 o; o.x = bcu(pkrtz(f0,f1)); o.y = bcu(pkrtz(f2,f3));
            myrow[q] = o;
        }
        invA[tid] = 1.0f / fmaxf(sqrtf(ssq), 1e-12f);
    }
    __syncthreads();                              // histogram + rows complete

    if (tid == 0) {
        int off = 0;
        for (int k = 1; k <= 20; k++) { base[k] = off; off += (cnt[k] + 63) & ~63; }
        *ntp = off >> 6;
    }
    __syncthreads();

    {
        int slot = base[cls] + myrank;
        perm[slot] = (unsigned short)tid;
        tcls[slot >> 6] = cls;                    // tile is class-pure: same value
    }
    __syncthreads();

    const int nt   = *ntp;
    const int wave = tid >> 6, lane = tid & 63;

    for (int t = wave; t < nt; t += NWAVE) {
        const int u = __builtin_amdgcn_readfirstlane(tcls[t]);   // uniform class
        const int local = perm[t*64 + lane];
        const bool mine = (local != 0xFFFF);
        const int lidx = mine ? local : 0;

        // per-lane cn row from LDS
        uint32 cnl[32];
        {
            const uint2* r2 = (const uint2*)lds + lidx * 17;
            #pragma unroll
            for (int q = 0; q < 16; q++) { uint2 v = r2[q]; cnl[2*q] = v.x; cnl[2*q+1] = v.y; }
        }
        const float inv = invA[lidx];

        // scores: wave-uniform K rows (scalar loads) x per-lane cn
        const uint32* kt = (const uint32*)(tabs + KN_OFF + (size_t)u * KN_KSTRIDE);
        float sc[20];
        #pragma unroll 2
        for (int j = 0; j < 20; j++) {
            const uint32* kj = kt + j*32;
            float a0 = 0.f, a1 = 0.f;
            #pragma unroll
            for (int q = 0; q < 16; q++) {
                a0 = dot2acc(bch2(cnl[2*q+0]), bch2(kj[2*q+0]), a0);
                a1 = dot2acc(bch2(cnl[2*q+1]), bch2(kj[2*q+1]), a1);
            }
            sc[j] = a0 + a1;
        }

        // softmax (cosines in [-1,1]: no max subtraction)
        float esum = 0.f;
        #pragma unroll
        for (int j = 0; j < 20; j++) { sc[j] = __expf(sc[j] * inv); esum += sc[j]; }
        const float wsc = 1.0f / esum;
        uint32 w2[11];
        #pragma unroll
        for (int jp = 0; jp < 10; jp++) w2[jp] = bcu(pkrtz(sc[2*jp]*wsc, sc[2*jp+1]*wsc));
        w2[10] = bcu(pkrtz(1.0f, 0.0f));          // embedded (rest,0) pair weight

        // PV: wave-uniform V rows (scalar loads); write f16 result over own row
        const uint32* vt = (const uint32*)(tabs + VAL_OFF + (size_t)u * VAL_KSTRIDE);
        uint2* wrow = (uint2*)lds + lidx * 17;
        #pragma unroll 2
        for (int c4 = 0; c4 < 16; c4++) {
            float acc[4];
            #pragma unroll
            for (int cc = 0; cc < 4; cc++) {
                const uint32* vr = vt + (c4*4 + cc) * 12;
                float a = 0.f;
                #pragma unroll
                for (int jp = 0; jp < 11; jp++) a = dot2acc(bch2(w2[jp]), bch2(vr[jp]), a);
                acc[cc] = a;
            }
            uint2 o; o.x = bcu(pkrtz(acc[0], acc[1])); o.y = bcu(pkrtz(acc[2], acc[3]));
            if (mine) wrow[c4] = o;
        }
    }
    __syncthreads();

    // coalesced f32 store from own row
    {
        const uint2* r2 = (const uint2*)lds + tid * 17;
        float* obase = out + (size_t)b * CDIM * HW + pim0 + tid;
        #pragma unroll
        for (int q = 0; q < 16; q++) {
            uint2 v = r2[q];
            h2 x = bch2(v.x), y = bch2(v.y);
            obase[(size_t)(4*q+0) * HW] = (float)x[0];
            obase[(size_t)(4*q+1) * HW] = (float)x[1];
            obase[(size_t)(4*q+2) * HW] = (float)y[0];
            obase[(size_t)(4*q+3) * HW] = (float)y[1];
        }
    }
}

extern "C" void kernel_launch(void* const* d_in, const int* in_sizes, int n_in,
                              void* d_out, int out_size, void* d_ws, size_t ws_size,
                              hipStream_t stream) {
    const float* content = (const float*)d_in[0];
    const int*   seg     = (const int*)d_in[1];
    const float* key     = (const float*)d_in[2];
    const float* val     = (const float*)d_in[3];
    float* out = (float*)d_out;
    unsigned char* ws = (unsigned char*)d_ws;

    prep_kernel<<<7, 256, 0, stream>>>(key, val, ws);

    (void)hipFuncSetAttribute((const void*)main_kernel,
                              hipFuncAttributeMaxDynamicSharedMemorySize, LDS_TOTAL);
    main_kernel<<<NPIX/BLK, BLK, LDS_TOTAL, stream>>>(content, seg, ws, out);
}

// Round 5
// 42.603 us; speedup vs baseline: 1.6503x; 1.6503x over previous
//
#include <hip/hip_runtime.h>

typedef _Float16 h2 __attribute__((ext_vector_type(2)));
typedef _Float16 h8 __attribute__((ext_vector_type(8)));
typedef float f4 __attribute__((ext_vector_type(4)));
typedef unsigned int uint32;

#define NVAL 20
#define CDIM 64
#define HW   65536
#define NPIX (4*HW)

#define BLK   512
#define NWAVE (BLK/64)
#define MAXTILES 28               // sum ceil(n_k/64) <= 8 + 19*(63/64) < 27
#define MAXSLOT  (MAXTILES*64)

// ---- packed f16 tables in ws (bytes) ----
// KN: per class 20 j-rows x 128 B (64 f16, c-contiguous)
#define KN_OFF      0
#define KN_KSTRIDE  2560
// VAL: per class 64 c-rows x 64 B (32 j-slots: j0..19 real, j20=rest, j21..31=0)
#define VAL_OFF     (20*KN_KSTRIDE)      // 51200
#define VAL_KSTRIDE 4096
#define VAL_CSTRIDE 64

// ---- LDS layout (bytes) ----
#define ROW_STRIDE 144            // 64 f16 (128 B) + 16 pad; 16B-aligned rows
#define ROWS_BYTES (BLK*ROW_STRIDE)          // 73728
#define INV_OFF   ROWS_BYTES                 // BLK f32
#define PERM_OFF  (INV_OFF + BLK*4)          // MAXSLOT ushort
#define TCLS_OFF  (PERM_OFF + MAXSLOT*2)     // MAXTILES int
#define CNT_OFF   (TCLS_OFF + MAXTILES*4)    // 24 int
#define BASE_OFF  (CNT_OFF + 24*4)           // 24 int
#define NT_OFF    (BASE_OFF + 24*4)
#define LDS_TOTAL (NT_OFF + 16)              // 79680 -> 2 blocks/CU

static __device__ __forceinline__ h2 bch2(uint32 u) { return __builtin_bit_cast(h2, u); }
static __device__ __forceinline__ uint32 bcu(h2 v) { return __builtin_bit_cast(uint32, v); }
static __device__ __forceinline__ h8 bch8(uint4 u) { return __builtin_bit_cast(h8, u); }
static __device__ __forceinline__ h2 pkrtz(float a, float b) {
    return __builtin_bit_cast(h2, __builtin_amdgcn_cvt_pkrtz(a, b));
}

// ---------------------------------------------------------------------------
// Prep: build packed f16 tables in ws.
// ---------------------------------------------------------------------------
__global__ void prep_kernel(const float* __restrict__ key,
                            const float* __restrict__ val,
                            unsigned char* __restrict__ ws) {
    int i = blockIdx.x * 256 + threadIdx.x;
    if (i < 20*CDIM) {
        int k = i >> 6, c = i & 63;
        const float* vb = val + k*NVAL*CDIM + c;     // val[k][j][c]
        float v[NVAL];
        float s = 0.f;
        #pragma unroll
        for (int j = 0; j < NVAL; j++) { v[j] = vb[j*CDIM]; s += v[j]; }
        float t = 0.f;
        for (int kk = 0; kk < 20; kk++) {
            const float* vb2 = val + kk*NVAL*CDIM + c;
            #pragma unroll
            for (int j = 0; j < NVAL; j++) t += vb2[j*CDIM];
        }
        float rest = (t - s) * (1.0f/NVAL);
        uint32* row = (uint32*)(ws + VAL_OFF + (size_t)k*VAL_KSTRIDE + c*VAL_CSTRIDE);
        #pragma unroll
        for (int jp = 0; jp < 10; jp++) row[jp] = bcu(pkrtz(v[2*jp], v[2*jp+1]));
        row[10] = bcu(pkrtz(rest, 0.f));
        #pragma unroll
        for (int jp = 11; jp < 16; jp++) row[jp] = 0u;
    } else if (i < 20*CDIM + 20*NVAL) {
        int idx = i - 20*CDIM;
        int k = idx / NVAL, j = idx % NVAL;
        const float* kb = key + k*CDIM*NVAL + j;     // key[k][c][j]
        float x[CDIM];
        float ssq = 0.f;
        #pragma unroll
        for (int c = 0; c < CDIM; c++) { x[c] = kb[c*NVAL]; ssq = fmaf(x[c], x[c], ssq); }
        float inv = 1.0f / fmaxf(sqrtf(ssq), 1e-12f);
        uint32* row = (uint32*)(ws + KN_OFF + (size_t)k*KN_KSTRIDE + j*128);
        #pragma unroll
        for (int cp = 0; cp < 32; cp++) row[cp] = bcu(pkrtz(x[2*cp]*inv, x[2*cp+1]*inv));
    }
}

// ---------------------------------------------------------------------------
// Main: 512 blocks x 512 threads. Counting-sort into class-pure 64-px tiles;
// per tile (one wave): S^T = Kn^T x X^T (16 MFMA), in-reg softmax (2 shfl),
// W via own LDS row, O^T = V^T x W^T (16 MFMA), O back to row, coalesced out.
// ---------------------------------------------------------------------------
__global__ __launch_bounds__(BLK, 4) void main_kernel(
        const float* __restrict__ content, const int* __restrict__ seg,
        const unsigned char* __restrict__ tabs, float* __restrict__ out) {
    extern __shared__ unsigned char lds[];
    float* invA = (float*)(lds + INV_OFF);
    unsigned short* perm = (unsigned short*)(lds + PERM_OFF);
    int* tcls = (int*)(lds + TCLS_OFF);
    int* cnt  = (int*)(lds + CNT_OFF);
    int* base = (int*)(lds + BASE_OFF);
    int* ntp  = (int*)(lds + NT_OFF);

    const int tid  = threadIdx.x;
    const int gp0  = blockIdx.x * BLK;
    const int b    = gp0 >> 16;
    const int pim0 = gp0 & (HW - 1);

    if (tid < 24) cnt[tid] = 0;
    for (int i = tid; i < MAXSLOT; i += BLK) perm[i] = 0xFFFFu;
    __syncthreads();

    const int cls = seg[gp0 + tid] + 1;          // 1..19
    const int myrank = atomicAdd(&cnt[cls], 1);

    // stage content -> own LDS row (f16, c-contiguous) + inv; coalesced reads
    {
        const float* cptr = content + (size_t)b * CDIM * HW + pim0 + tid;
        uint2* myrow = (uint2*)(lds + tid * ROW_STRIDE);
        float ssq = 0.f;
        #pragma unroll
        for (int q = 0; q < 16; q++) {
            float f0 = cptr[(size_t)(4*q+0) * HW];
            float f1 = cptr[(size_t)(4*q+1) * HW];
            float f2 = cptr[(size_t)(4*q+2) * HW];
            float f3 = cptr[(size_t)(4*q+3) * HW];
            ssq = fmaf(f0,f0,ssq); ssq = fmaf(f1,f1,ssq);
            ssq = fmaf(f2,f2,ssq); ssq = fmaf(f3,f3,ssq);
            uint2 o; o.x = bcu(pkrtz(f0,f1)); o.y = bcu(pkrtz(f2,f3));
            myrow[q] = o;
        }
        invA[tid] = 1.0f / fmaxf(sqrtf(ssq), 1e-12f);
    }
    __syncthreads();

    if (tid == 0) {
        int off = 0;
        for (int k = 1; k <= 20; k++) { base[k] = off; off += (cnt[k] + 63) & ~63; }
        *ntp = off >> 6;
    }
    __syncthreads();
    {
        int slot = base[cls] + myrank;
        perm[slot] = (unsigned short)tid;
        tcls[slot >> 6] = cls;                   // class-pure tile
    }
    __syncthreads();

    const int nt   = *ntp;
    const int wave = tid >> 6, lane = tid & 63;
    const int g = lane >> 4, r16 = lane & 15;

    for (int t = wave; t < nt; t += NWAVE) {
        const int u = __builtin_amdgcn_readfirstlane(tcls[t]);

        // per-nsub pixel bookkeeping (n covers pixels n*16 + r16)
        int rowb0, rowb1, rowb2, rowb3;
        float inv0, inv1, inv2, inv3;
        bool mn0, mn1, mn2, mn3;
        {
            int v0 = perm[t*64 + 0*16 + r16]; mn0 = (v0 != 0xFFFF); int l0 = mn0 ? v0 : 0;
            int v1 = perm[t*64 + 1*16 + r16]; mn1 = (v1 != 0xFFFF); int l1 = mn1 ? v1 : 0;
            int v2 = perm[t*64 + 2*16 + r16]; mn2 = (v2 != 0xFFFF); int l2 = mn2 ? v2 : 0;
            int v3 = perm[t*64 + 3*16 + r16]; mn3 = (v3 != 0xFFFF); int l3 = mn3 ? v3 : 0;
            rowb0 = l0*ROW_STRIDE; rowb1 = l1*ROW_STRIDE;
            rowb2 = l2*ROW_STRIDE; rowb3 = l3*ROW_STRIDE;
            inv0 = invA[l0]; inv1 = invA[l1]; inv2 = invA[l2]; inv3 = invA[l3];
        }
        const int rowb[4] = {rowb0, rowb1, rowb2, rowb3};
        const float invn[4] = {inv0, inv1, inv2, inv3};
        const bool mine[4] = {mn0, mn1, mn2, mn3};

        // ---- scores S^T[j][p] = sum_c Kn^T[j][c] * X^T[c][p] ----
        // A-frag (Kn^T): row j = m*16+r16, k c = ks*32+g*8 (16B from KN row j)
        const unsigned char* knc = tabs + KN_OFF + (size_t)u * KN_KSTRIDE;
        uint4 a_sc[2][2];
        #pragma unroll
        for (int m = 0; m < 2; m++)
            #pragma unroll
            for (int ks = 0; ks < 2; ks++)
                a_sc[m][ks] = *(const uint4*)(knc + (m*16 + r16)*128 + (ks*32 + g*8)*2);
        // B-frag (X^T): col p = n*16+r16, k c = ks*32+g*8 (16B from pixel row)
        uint4 b_sc[4][2];
        #pragma unroll
        for (int n = 0; n < 4; n++)
            #pragma unroll
            for (int ks = 0; ks < 2; ks++)
                b_sc[n][ks] = *(const uint4*)(lds + rowb[n] + (ks*32 + g*8)*2);

        f4 sacc[2][4];
        #pragma unroll
        for (int m = 0; m < 2; m++)
            #pragma unroll
            for (int n = 0; n < 4; n++) sacc[m][n] = (f4){0.f,0.f,0.f,0.f};
        #pragma unroll
        for (int ks = 0; ks < 2; ks++)
            #pragma unroll
            for (int m = 0; m < 2; m++)
                #pragma unroll
                for (int n = 0; n < 4; n++)
                    sacc[m][n] = __builtin_amdgcn_mfma_f32_16x16x32_f16(
                        bch8(a_sc[m][ks]), bch8(b_sc[n][ks]), sacc[m][n], 0, 0, 0);

        // ---- softmax; lane holds j = m*16 + g*4 + r for pixel p = n*16+r16 ----
        uint2 w0[4], w1[4];
        #pragma unroll
        for (int n = 0; n < 4; n++) {
            float e0[4], e1[4];
            #pragma unroll
            for (int r = 0; r < 4; r++) e0[r] = __expf(sacc[0][n][r] * invn[n]);
            float arg1 = (g == 0) ? invn[n] : 0.0f;     // j>=20 masked (exp(0), unused)
            #pragma unroll
            for (int r = 0; r < 4; r++) e1[r] = __expf(sacc[1][n][r] * arg1);
            float s = e0[0]+e0[1]+e0[2]+e0[3];
            s += (g == 0) ? (e1[0]+e1[1]+e1[2]+e1[3]) : 0.0f;
            s += __shfl_xor(s, 16, 64);
            s += __shfl_xor(s, 32, 64);
            float wsc = 1.0f / s;
            w0[n].x = bcu(pkrtz(e0[0]*wsc, e0[1]*wsc));
            w0[n].y = bcu(pkrtz(e0[2]*wsc, e0[3]*wsc));
            uint2 t1;
            if (g == 0)      { t1.x = bcu(pkrtz(e1[0]*wsc, e1[1]*wsc));
                               t1.y = bcu(pkrtz(e1[2]*wsc, e1[3]*wsc)); }
            else if (g == 1) { t1.x = 0x00003C00u; t1.y = 0u; }  // j20=1.0 (rest), j21..23=0
            else             { t1.x = 0u; t1.y = 0u; }            // j24..31=0
            w1[n] = t1;
        }
        // write W over own row (X is dead): j-contiguous 32 f16 at offset 0
        #pragma unroll
        for (int n = 0; n < 4; n++) {
            if (mine[n]) {
                *(uint2*)(lds + rowb[n] + g*8)      = w0[n];   // j = g*4..g*4+3
                *(uint2*)(lds + rowb[n] + 32 + g*8) = w1[n];   // j = 16+g*4..
            }
        }

        // ---- PV O^T[c][p] = sum_j V^T[c][j] * W^T[j][p] (K=32) ----
        // B-frag (W^T): col p = n*16+r16, k j = g*8 (16B from pixel row)
        uint4 b_pv[4];
        #pragma unroll
        for (int n = 0; n < 4; n++)
            b_pv[n] = *(const uint4*)(lds + rowb[n] + g*16);
        // A-frag (V^T): row c = m*16+r16, k j = g*8 (16B from VAL row c)
        const unsigned char* vc = tabs + VAL_OFF + (size_t)u * VAL_KSTRIDE;
        #pragma unroll
        for (int m = 0; m < 4; m++) {
            uint4 a = *(const uint4*)(vc + (m*16 + r16)*VAL_CSTRIDE + g*16);
            #pragma unroll
            for (int n = 0; n < 4; n++) {
                f4 o = (f4){0.f,0.f,0.f,0.f};
                o = __builtin_amdgcn_mfma_f32_16x16x32_f16(bch8(a), bch8(b_pv[n]), o, 0, 0, 0);
                uint2 ov; ov.x = bcu(pkrtz(o[0], o[1])); ov.y = bcu(pkrtz(o[2], o[3]));
                if (mine[n])
                    *(uint2*)(lds + rowb[n] + m*32 + g*8) = ov;  // c = m*16+g*4..+3
            }
        }
    }
    __syncthreads();

    // coalesced f32 store from own row
    {
        const uint2* r2 = (const uint2*)(lds + tid * ROW_STRIDE);
        float* obase = out + (size_t)b * CDIM * HW + pim0 + tid;
        #pragma unroll
        for (int q = 0; q < 16; q++) {
            uint2 v = r2[q];
            h2 x = bch2(v.x), y = bch2(v.y);
            obase[(size_t)(4*q+0) * HW] = (float)x[0];
            obase[(size_t)(4*q+1) * HW] = (float)x[1];
            obase[(size_t)(4*q+2) * HW] = (float)y[0];
            obase[(size_t)(4*q+3) * HW] = (float)y[1];
        }
    }
}

extern "C" void kernel_launch(void* const* d_in, const int* in_sizes, int n_in,
                              void* d_out, int out_size, void* d_ws, size_t ws_size,
                              hipStream_t stream) {
    const float* content = (const float*)d_in[0];
    const int*   seg     = (const int*)d_in[1];
    const float* key     = (const float*)d_in[2];
    const float* val     = (const float*)d_in[3];
    float* out = (float*)d_out;
    unsigned char* ws = (unsigned char*)d_ws;

    prep_kernel<<<7, 256, 0, stream>>>(key, val, ws);

    (void)hipFuncSetAttribute((const void*)main_kernel,
                              hipFuncAttributeMaxDynamicSharedMemorySize, LDS_TOTAL);
    main_kernel<<<NPIX/BLK, BLK, LDS_TOTAL, stream>>>(content, seg, ws, out);
}